// Round 1
// baseline (1524.209 us; speedup 1.0000x reference)
//
#include <hip/hip_runtime.h>
#include <hip/hip_bf16.h>

#define B 32
#define S 2048
#define E 1024
#define H 1024
#define MASK_VAL -50000.0f

__device__ __forceinline__ float fast_tanh(float x) {
    float a = fabsf(x);
    float e = __expf(-2.0f * a);
    float t = (1.0f - e) / (1.0f + e);
    return copysignf(t, x);
}

// K1: dec_proj[b][h] = sum_d dec[b][d] * W[h][1024+d]
__global__ __launch_bounds__(256) void k1_decproj(
    const float* __restrict__ dec, const float* __restrict__ W,
    float* __restrict__ dec_proj)
{
    int gid = blockIdx.x * 256 + threadIdx.x;   // 32768 total
    int b = gid >> 10, h = gid & 1023;
    const float4* wd = (const float4*)(W + (long)h * 2048 + 1024);
    const float4* dd = (const float4*)(dec + b * 1024);
    float acc = 0.f;
    for (int d = 0; d < 256; ++d) {
        float4 w4 = wd[d], d4 = dd[d];
        acc += w4.x * d4.x + w4.y * d4.y + w4.z * d4.z + w4.w * d4.w;
    }
    dec_proj[gid] = acc;
}

// K2: logits[b][s] = sum_h v[h] * tanh( enc[b][s][:]·W[h][:1024] + dec_proj[b][h] )
// Tile: 64 rows (s) x 128 cols (h), BK=16. 256 threads, 4x8 micro-tile each.
__global__ __launch_bounds__(256) void k2_logits(
    const float* __restrict__ enc, const float* __restrict__ W,
    const float* __restrict__ v, const float* __restrict__ dec_proj,
    const int* __restrict__ seq, float* __restrict__ logits)
{
    const int b = blockIdx.y;
    const int s0 = blockIdx.x * 64;
    if (s0 >= seq[b]) return;   // masked rows -> attn == 0, never read
    const int tid = threadIdx.x;
    const int tx4 = (tid & 15) * 4;   // col group
    const int ty4 = (tid >> 4) * 4;   // row group

    __shared__ float As[16][68];    // [k][m], padded
    __shared__ float Bs[16][132];   // [k][n], padded

    const int lm = tid >> 2;        // 0..63
    const int lk = (tid & 3) * 4;   // 0,4,8,12

    const float* encA = enc + ((long)b * S + s0 + lm) * E + lk;

    float lp[4] = {0.f, 0.f, 0.f, 0.f};

    for (int nt = 0; nt < 8; ++nt) {
        const int h0 = nt * 128;
        float acc[4][8];
        #pragma unroll
        for (int i = 0; i < 4; ++i)
            #pragma unroll
            for (int j = 0; j < 8; ++j) acc[i][j] = 0.f;

        for (int kt = 0; kt < 64; ++kt) {
            const int e0 = kt * 16;
            float4 av  = *(const float4*)(encA + e0);
            float4 bv0 = *(const float4*)(&W[(long)(h0 + lm) * 2048 + e0 + lk]);
            float4 bv1 = *(const float4*)(&W[(long)(h0 + 64 + lm) * 2048 + e0 + lk]);
            __syncthreads();
            As[lk + 0][lm] = av.x;  As[lk + 1][lm] = av.y;
            As[lk + 2][lm] = av.z;  As[lk + 3][lm] = av.w;
            Bs[lk + 0][lm] = bv0.x; Bs[lk + 1][lm] = bv0.y;
            Bs[lk + 2][lm] = bv0.z; Bs[lk + 3][lm] = bv0.w;
            Bs[lk + 0][lm + 64] = bv1.x; Bs[lk + 1][lm + 64] = bv1.y;
            Bs[lk + 2][lm + 64] = bv1.z; Bs[lk + 3][lm + 64] = bv1.w;
            __syncthreads();
            #pragma unroll
            for (int k = 0; k < 16; ++k) {
                float4 a  = *(const float4*)&As[k][ty4];
                float4 b0 = *(const float4*)&Bs[k][tx4];
                float4 b1 = *(const float4*)&Bs[k][tx4 + 64];
                float am[4] = {a.x, a.y, a.z, a.w};
                float bn[8] = {b0.x, b0.y, b0.z, b0.w, b1.x, b1.y, b1.z, b1.w};
                #pragma unroll
                for (int i = 0; i < 4; ++i)
                    #pragma unroll
                    for (int j = 0; j < 8; ++j)
                        acc[i][j] = fmaf(am[i], bn[j], acc[i][j]);
            }
        }
        // finalize this h-tile: tanh + weight by v, accumulate into logit partials
        float4 dp0 = *(const float4*)&dec_proj[b * H + h0 + tx4];
        float4 dp1 = *(const float4*)&dec_proj[b * H + h0 + 64 + tx4];
        float4 v0  = *(const float4*)&v[h0 + tx4];
        float4 v1  = *(const float4*)&v[h0 + 64 + tx4];
        float dpj[8] = {dp0.x, dp0.y, dp0.z, dp0.w, dp1.x, dp1.y, dp1.z, dp1.w};
        float vj[8]  = {v0.x, v0.y, v0.z, v0.w, v1.x, v1.y, v1.z, v1.w};
        #pragma unroll
        for (int i = 0; i < 4; ++i) {
            float t = 0.f;
            #pragma unroll
            for (int j = 0; j < 8; ++j)
                t += vj[j] * fast_tanh(acc[i][j] + dpj[j]);
            lp[i] += t;
        }
    }
    // reduce lp over the 16 tx lanes (lane bits 0..3)
    #pragma unroll
    for (int i = 0; i < 4; ++i) {
        float t = lp[i];
        t += __shfl_xor(t, 1);
        t += __shfl_xor(t, 2);
        t += __shfl_xor(t, 4);
        t += __shfl_xor(t, 8);
        lp[i] = t;
    }
    if ((tid & 15) == 0) {
        int m = (tid >> 4) * 4;
        #pragma unroll
        for (int i = 0; i < 4; ++i)
            logits[b * S + s0 + m + i] = lp[i];
    }
}

// K3: masked softmax over s per batch
__global__ __launch_bounds__(256) void k3_softmax(
    const float* __restrict__ logits, const int* __restrict__ seq,
    float* __restrict__ attn)
{
    int b = blockIdx.x, tid = threadIdx.x;
    int len = seq[b];
    float vals[8];
    float mx = -3.4e38f;
    #pragma unroll
    for (int i = 0; i < 8; ++i) {
        int s = i * 256 + tid;
        float x = (s < len) ? logits[b * S + s] : MASK_VAL;
        vals[i] = x;
        mx = fmaxf(mx, x);
    }
    #pragma unroll
    for (int off = 1; off < 64; off <<= 1) mx = fmaxf(mx, __shfl_xor(mx, off));
    __shared__ float red[8];
    int wave = tid >> 6, lane = tid & 63;
    if (lane == 0) red[wave] = mx;
    __syncthreads();
    mx = fmaxf(fmaxf(red[0], red[1]), fmaxf(red[2], red[3]));
    float e[8];
    float sum = 0.f;
    #pragma unroll
    for (int i = 0; i < 8; ++i) { e[i] = __expf(vals[i] - mx); sum += e[i]; }
    #pragma unroll
    for (int off = 1; off < 64; off <<= 1) sum += __shfl_xor(sum, off);
    if (lane == 0) red[4 + wave] = sum;
    __syncthreads();
    sum = red[4] + red[5] + red[6] + red[7];
    float inv = 1.0f / sum;
    #pragma unroll
    for (int i = 0; i < 8; ++i) attn[b * S + i * 256 + tid] = e[i] * inv;
}

// K4: partial[b][c][e] = sum_{s in chunk c} attn[b][s] * enc[b][s][e]
__global__ __launch_bounds__(256) void k4_partial(
    const float* __restrict__ enc, const float* __restrict__ attn,
    const int* __restrict__ seq, float* __restrict__ partial)
{
    int c = blockIdx.x, b = blockIdx.y, tid = threadIdx.x;
    int base_s = c * 256;
    int len = seq[b];
    float4 acc = make_float4(0.f, 0.f, 0.f, 0.f);
    if (base_s < len) {
        int s_end = min(256, len - base_s);
        const float* ep = enc + ((long)b * S + base_s) * E + tid * 4;
        const float* ap = attn + b * S + base_s;
        for (int s = 0; s < s_end; ++s) {
            float w = ap[s];
            float4 ev = *(const float4*)ep;
            ep += E;
            acc.x += w * ev.x; acc.y += w * ev.y;
            acc.z += w * ev.z; acc.w += w * ev.w;
        }
    }
    *(float4*)(&partial[((b * 8) + c) * 1024 + tid * 4]) = acc;
}

// K5: out[b][e] = sum_c partial[b][c][e]
__global__ __launch_bounds__(256) void k5_reduce(
    const float* __restrict__ partial, float* __restrict__ out)
{
    int gid = blockIdx.x * 256 + threadIdx.x;  // 32768 = B*E
    int b = gid >> 10, e = gid & 1023;
    float s = 0.f;
    #pragma unroll
    for (int c = 0; c < 8; ++c) s += partial[(b * 8 + c) * 1024 + e];
    out[gid] = s;
}

extern "C" void kernel_launch(void* const* d_in, const int* in_sizes, int n_in,
                              void* d_out, int out_size, void* d_ws, size_t ws_size,
                              hipStream_t stream)
{
    const float* enc = (const float*)d_in[0];
    const int*   seq = (const int*)d_in[1];
    const float* dec = (const float*)d_in[2];
    const float* W   = (const float*)d_in[3];
    const float* v   = (const float*)d_in[4];

    float* out  = (float*)d_out;            // (B, E)
    float* attn = out + B * E;              // (B, S)

    float* dec_proj = (float*)d_ws;         // B*H floats
    float* logits   = dec_proj + B * H;     // B*S floats
    float* partial  = logits + B * S;       // B*8*1024 floats

    hipLaunchKernelGGL(k1_decproj, dim3(B * H / 256), dim3(256), 0, stream,
                       dec, W, dec_proj);
    hipLaunchKernelGGL(k2_logits, dim3(S / 64, B), dim3(256), 0, stream,
                       enc, W, v, dec_proj, seq, logits);
    hipLaunchKernelGGL(k3_softmax, dim3(B), dim3(256), 0, stream,
                       logits, seq, attn);
    hipLaunchKernelGGL(k4_partial, dim3(8, B), dim3(256), 0, stream,
                       enc, attn, seq, partial);
    hipLaunchKernelGGL(k5_reduce, dim3(B * E / 256), dim3(256), 0, stream,
                       partial, out);
}

// Round 2
// 802.606 us; speedup vs baseline: 1.8991x; 1.8991x over previous
//
#include <hip/hip_runtime.h>
#include <hip/hip_bf16.h>

#define B 32
#define S 2048
#define E 1024
#define H 1024
#define MASK_VAL -50000.0f

typedef __attribute__((ext_vector_type(8))) short bf16x8_t;
typedef __attribute__((ext_vector_type(4))) float f32x4_t;

__device__ __forceinline__ float fast_tanh(float x) {
    float a = fabsf(x);
    float e = __expf(-2.0f * a);
    float t = (1.0f - e) / (1.0f + e);
    return copysignf(t, x);
}

__device__ __forceinline__ bf16x8_t cvt8(const float4 f0, const float4 f1) {
    union { bf16x8_t s8; __hip_bfloat162 h[4]; } u;
    u.h[0] = __float22bfloat162_rn(make_float2(f0.x, f0.y));
    u.h[1] = __float22bfloat162_rn(make_float2(f0.z, f0.w));
    u.h[2] = __float22bfloat162_rn(make_float2(f1.x, f1.y));
    u.h[3] = __float22bfloat162_rn(make_float2(f1.z, f1.w));
    return u.s8;
}

// kW: convert W[:, :1024] (fp32, row stride 2048) -> Wb[h][e] bf16
__global__ __launch_bounds__(256) void kW_conv(
    const float* __restrict__ W, __hip_bfloat16* __restrict__ Wb)
{
    int idx = (blockIdx.x * 256 + threadIdx.x) * 4;   // over H*E = 1M elems
    int h = idx >> 10, e = idx & 1023;
    float4 f = *(const float4*)(W + (size_t)h * 2048 + e);
    __hip_bfloat162 p0 = __float22bfloat162_rn(make_float2(f.x, f.y));
    __hip_bfloat162 p1 = __float22bfloat162_rn(make_float2(f.z, f.w));
    *reinterpret_cast<__hip_bfloat162*>(Wb + idx)     = p0;
    *reinterpret_cast<__hip_bfloat162*>(Wb + idx + 2) = p1;
}

// K1: dec_proj[b][h] = sum_d dec[b][d] * W[h][1024+d]   (fp32, tiny)
__global__ __launch_bounds__(256) void k1_decproj(
    const float* __restrict__ dec, const float* __restrict__ W,
    float* __restrict__ dec_proj)
{
    int gid = blockIdx.x * 256 + threadIdx.x;   // 32768 total
    int b = gid >> 10, h = gid & 1023;
    const float4* wd = (const float4*)(W + (size_t)h * 2048 + 1024);
    const float4* dd = (const float4*)(dec + b * 1024);
    float acc = 0.f;
    for (int d = 0; d < 256; ++d) {
        float4 w4 = wd[d], d4 = dd[d];
        acc += w4.x * d4.x + w4.y * d4.y + w4.z * d4.z + w4.w * d4.w;
    }
    dec_proj[gid] = acc;
}

// K2: MFMA bf16 GEMM (s x h tile 128x128, K=E=1024) fused with tanh + v-dot.
// Writes per-64h partial logits: part[b][s][16].
// No LDS: A frags loaded direct from fp32 enc + cvt in-register; B frags
// direct from bf16 Wb (both are [row][k] K-major, matching frag layouts).
__global__ __launch_bounds__(256) void k2_mfma(
    const float* __restrict__ enc, const __hip_bfloat16* __restrict__ Wb,
    const float* __restrict__ v, const float* __restrict__ dec_proj,
    const int* __restrict__ seq, float* __restrict__ part)
{
    const int b  = blockIdx.y;
    const int s0 = blockIdx.x * 128;
    if (s0 >= seq[b]) return;
    const int ht = blockIdx.z;
    const int h0 = ht * 128;

    const int tid  = threadIdx.x;
    const int wave = tid >> 6;
    const int lane = tid & 63;
    const int wr = wave >> 1, wc = wave & 1;   // 2x2 wave grid
    const int cr = lane & 15;                  // row/col within fragment
    const int cg = lane >> 4;                  // k sub-group

    const float* Abase = enc + ((size_t)b * S + s0 + wr * 64 + cr) * E + cg * 8;
    const __hip_bfloat16* Bbase = Wb + (size_t)(h0 + wc * 64 + cr) * E + cg * 8;

    f32x4_t acc[4][4];
    #pragma unroll
    for (int m = 0; m < 4; ++m)
        #pragma unroll
        for (int n = 0; n < 4; ++n)
            acc[m][n] = (f32x4_t){0.f, 0.f, 0.f, 0.f};

    for (int kt = 0; kt < 16; ++kt) {
        const int e0 = kt * 64;
        bf16x8_t afr[2][4], bfr[2][4];
        #pragma unroll
        for (int ks = 0; ks < 2; ++ks)
            #pragma unroll
            for (int m = 0; m < 4; ++m) {
                const float* ap = Abase + e0 + ks * 32 + m * 16 * E;
                afr[ks][m] = cvt8(*(const float4*)ap, *(const float4*)(ap + 4));
            }
        #pragma unroll
        for (int ks = 0; ks < 2; ++ks)
            #pragma unroll
            for (int n = 0; n < 4; ++n)
                bfr[ks][n] = *(const bf16x8_t*)(Bbase + e0 + ks * 32 + n * 16 * E);
        #pragma unroll
        for (int ks = 0; ks < 2; ++ks)
            #pragma unroll
            for (int m = 0; m < 4; ++m)
                #pragma unroll
                for (int n = 0; n < 4; ++n)
                    acc[m][n] = __builtin_amdgcn_mfma_f32_16x16x32_bf16(
                        afr[ks][m], bfr[ks][n], acc[m][n], 0, 0, 0);
    }

    // Epilogue: x = acc + dec_proj; t = v*tanh(x); reduce over 16 h-cols/lane-group.
    float vv[4], dp[4];
    #pragma unroll
    for (int n = 0; n < 4; ++n) {
        int h = h0 + wc * 64 + n * 16 + cr;
        vv[n] = v[h];
        dp[n] = dec_proj[b * H + h];
    }
    #pragma unroll
    for (int m = 0; m < 4; ++m) {
        #pragma unroll
        for (int j = 0; j < 4; ++j) {
            float t = 0.f;
            #pragma unroll
            for (int n = 0; n < 4; ++n)
                t += vv[n] * fast_tanh(acc[m][n][j] + dp[n]);
            t += __shfl_xor(t, 1);
            t += __shfl_xor(t, 2);
            t += __shfl_xor(t, 4);
            t += __shfl_xor(t, 8);
            if (cr == 0) {
                int srow = s0 + wr * 64 + m * 16 + cg * 4 + j;
                part[(size_t)(b * S + srow) * 16 + ht * 2 + wc] = t;
            }
        }
    }
}

// K3: sum 16 partials -> logit; masked softmax over s per batch
__global__ __launch_bounds__(256) void k3_softmax(
    const float* __restrict__ part, const int* __restrict__ seq,
    float* __restrict__ attn)
{
    int b = blockIdx.x, tid = threadIdx.x;
    int len = seq[b];
    float vals[8];
    float mx = -3.4e38f;
    #pragma unroll
    for (int i = 0; i < 8; ++i) {
        int s = i * 256 + tid;
        float x = MASK_VAL;
        if (s < len) {
            const f32x4_t* p = (const f32x4_t*)&part[(size_t)(b * S + s) * 16];
            f32x4_t a = p[0], c = p[1], d = p[2], e = p[3];
            x = (a[0] + a[1] + a[2] + a[3]) + (c[0] + c[1] + c[2] + c[3]) +
                (d[0] + d[1] + d[2] + d[3]) + (e[0] + e[1] + e[2] + e[3]);
        }
        vals[i] = x;
        mx = fmaxf(mx, x);
    }
    #pragma unroll
    for (int off = 1; off < 64; off <<= 1) mx = fmaxf(mx, __shfl_xor(mx, off));
    __shared__ float red[8];
    int wave = tid >> 6, lane = tid & 63;
    if (lane == 0) red[wave] = mx;
    __syncthreads();
    mx = fmaxf(fmaxf(red[0], red[1]), fmaxf(red[2], red[3]));
    float e[8];
    float sum = 0.f;
    #pragma unroll
    for (int i = 0; i < 8; ++i) { e[i] = __expf(vals[i] - mx); sum += e[i]; }
    #pragma unroll
    for (int off = 1; off < 64; off <<= 1) sum += __shfl_xor(sum, off);
    if (lane == 0) red[4 + wave] = sum;
    __syncthreads();
    sum = red[4] + red[5] + red[6] + red[7];
    float inv = 1.0f / sum;
    #pragma unroll
    for (int i = 0; i < 8; ++i) attn[b * S + i * 256 + tid] = e[i] * inv;
}

// K4: opart[b][c][e] = sum_{s in chunk c} attn[b][s] * enc[b][s][e]
__global__ __launch_bounds__(256) void k4_partial(
    const float* __restrict__ enc, const float* __restrict__ attn,
    const int* __restrict__ seq, float* __restrict__ opart)
{
    int c = blockIdx.x, b = blockIdx.y, tid = threadIdx.x;
    int base_s = c * 256;
    int len = seq[b];
    float4 acc = make_float4(0.f, 0.f, 0.f, 0.f);
    if (base_s < len) {
        int s_end = min(256, len - base_s);
        const float* ep = enc + ((size_t)b * S + base_s) * E + tid * 4;
        const float* ap = attn + b * S + base_s;
        for (int s = 0; s < s_end; ++s) {
            float w = ap[s];
            float4 ev = *(const float4*)ep;
            ep += E;
            acc.x += w * ev.x; acc.y += w * ev.y;
            acc.z += w * ev.z; acc.w += w * ev.w;
        }
    }
    *(float4*)(&opart[((b * 8) + c) * 1024 + tid * 4]) = acc;
}

// K5: out[b][e] = sum_c opart[b][c][e]
__global__ __launch_bounds__(256) void k5_reduce(
    const float* __restrict__ opart, float* __restrict__ out)
{
    int gid = blockIdx.x * 256 + threadIdx.x;  // 32768 = B*E
    int b = gid >> 10, e = gid & 1023;
    float s = 0.f;
    #pragma unroll
    for (int c = 0; c < 8; ++c) s += opart[(b * 8 + c) * 1024 + e];
    out[gid] = s;
}

extern "C" void kernel_launch(void* const* d_in, const int* in_sizes, int n_in,
                              void* d_out, int out_size, void* d_ws, size_t ws_size,
                              hipStream_t stream)
{
    const float* enc = (const float*)d_in[0];
    const int*   seq = (const int*)d_in[1];
    const float* dec = (const float*)d_in[2];
    const float* W   = (const float*)d_in[3];
    const float* v   = (const float*)d_in[4];

    float* out  = (float*)d_out;            // (B, E)
    float* attn = out + B * E;              // (B, S)

    float* dec_proj = (float*)d_ws;                         // B*H
    float* part     = dec_proj + B * H;                     // B*S*16
    float* opart    = part + (size_t)B * S * 16;            // B*8*1024
    __hip_bfloat16* Wb = (__hip_bfloat16*)(opart + B * 8 * 1024);  // H*E bf16

    hipLaunchKernelGGL(kW_conv, dim3(H * E / 1024), dim3(256), 0, stream, W, Wb);
    hipLaunchKernelGGL(k1_decproj, dim3(B * H / 256), dim3(256), 0, stream,
                       dec, W, dec_proj);
    hipLaunchKernelGGL(k2_mfma, dim3(S / 128, B, H / 128), dim3(256), 0, stream,
                       enc, Wb, v, dec_proj, seq, part);
    hipLaunchKernelGGL(k3_softmax, dim3(B), dim3(256), 0, stream,
                       part, seq, attn);
    hipLaunchKernelGGL(k4_partial, dim3(8, B), dim3(256), 0, stream,
                       enc, attn, seq, opart);
    hipLaunchKernelGGL(k5_reduce, dim3(B * E / 256), dim3(256), 0, stream,
                       opart, out);
}

// Round 3
// 368.118 us; speedup vs baseline: 4.1405x; 2.1803x over previous
//
#include <hip/hip_runtime.h>
#include <hip/hip_bf16.h>

#define B 32
#define S 2048
#define E 1024
#define H 1024
#define MASK_VAL -50000.0f

typedef __attribute__((ext_vector_type(8))) short bf16x8_t;
typedef __attribute__((ext_vector_type(4))) float f32x4_t;

__device__ __forceinline__ float fast_tanh(float x) {
    float a = fabsf(x);
    float e = __expf(-2.0f * a);
    float t = (1.0f - e) / (1.0f + e);
    return copysignf(t, x);
}

__device__ __forceinline__ bf16x8_t cvt8(const float4 f0, const float4 f1) {
    union { bf16x8_t s8; __hip_bfloat162 h[4]; } u;
    u.h[0] = __float22bfloat162_rn(make_float2(f0.x, f0.y));
    u.h[1] = __float22bfloat162_rn(make_float2(f0.z, f0.w));
    u.h[2] = __float22bfloat162_rn(make_float2(f1.x, f1.y));
    u.h[3] = __float22bfloat162_rn(make_float2(f1.z, f1.w));
    return u.s8;
}

__device__ __forceinline__ void gload16(const void* g, void* l) {
    __builtin_amdgcn_global_load_lds(
        (const __attribute__((address_space(1))) void*)g,
        (__attribute__((address_space(3))) void*)l, 16, 0, 0);
}

// k0: enc fp32 -> bf16 for active (tile-rounded) rows only
__global__ __launch_bounds__(256) void k0_encconv(
    const float* __restrict__ enc, const int* __restrict__ seq,
    __hip_bfloat16* __restrict__ encb)
{
    int c = blockIdx.x, b = blockIdx.y;
    if (c * 128 >= seq[b]) return;
    size_t base = ((size_t)b * S + c * 128) * E;
    const float* src = enc + base;
    __hip_bfloat16* dst = encb + base;
    int tid = threadIdx.x;
    #pragma unroll 4
    for (int it = 0; it < 64; ++it) {
        int idx = it * 2048 + tid * 8;
        float4 f0 = *(const float4*)(src + idx);
        float4 f1 = *(const float4*)(src + idx + 4);
        *(bf16x8_t*)(dst + idx) = cvt8(f0, f1);
    }
}

// kW: convert W[:, :1024] (fp32, row stride 2048) -> Wb[h][e] bf16
__global__ __launch_bounds__(256) void kW_conv(
    const float* __restrict__ W, __hip_bfloat16* __restrict__ Wb)
{
    int idx = (blockIdx.x * 256 + threadIdx.x) * 4;   // over H*E = 1M elems
    int h = idx >> 10, e = idx & 1023;
    float4 f = *(const float4*)(W + (size_t)h * 2048 + e);
    __hip_bfloat162 p0 = __float22bfloat162_rn(make_float2(f.x, f.y));
    __hip_bfloat162 p1 = __float22bfloat162_rn(make_float2(f.z, f.w));
    *reinterpret_cast<__hip_bfloat162*>(Wb + idx)     = p0;
    *reinterpret_cast<__hip_bfloat162*>(Wb + idx + 2) = p1;
}

// K1: dec_proj[b][h] = sum_d dec[b][d] * W[h][1024+d]   (fp32, tiny)
__global__ __launch_bounds__(256) void k1_decproj(
    const float* __restrict__ dec, const float* __restrict__ W,
    float* __restrict__ dec_proj)
{
    int gid = blockIdx.x * 256 + threadIdx.x;   // 32768 total
    int b = gid >> 10, h = gid & 1023;
    const float4* wd = (const float4*)(W + (size_t)h * 2048 + 1024);
    const float4* dd = (const float4*)(dec + b * 1024);
    float acc = 0.f;
    for (int d = 0; d < 256; ++d) {
        float4 w4 = wd[d], d4 = dd[d];
        acc += w4.x * d4.x + w4.y * d4.y + w4.z * d4.z + w4.w * d4.w;
    }
    dec_proj[gid] = acc;
}

// K2: LDS-staged bf16 MFMA GEMM, 128(s) x 128(h) tile, BK=64, K=1024.
// AMODE 0: A via global_load_lds from pre-converted encb (linear LDS dest,
//          pre-swizzled global source). AMODE 1: A reg-staged from fp32 enc
//          (cvt in-reg, ds_write at swizzled addr). B always global_load_lds.
// LDS tiles [128 rows][128 bytes]; byte col XOR-swizzled by (row&7)<<4 so the
// stride-128B ds_read_b128 frag reads are 2-way (free) instead of 16-way.
template<int AMODE>
__global__ __launch_bounds__(256) void k2_mfma(
    const float* __restrict__ enc, const __hip_bfloat16* __restrict__ encb,
    const __hip_bfloat16* __restrict__ Wb, const float* __restrict__ v,
    const float* __restrict__ dec_proj, const int* __restrict__ seq,
    float* __restrict__ part)
{
    const int b  = blockIdx.y;
    const int s0 = blockIdx.x * 128;
    if (s0 >= seq[b]) return;
    const int ht = blockIdx.z;
    const int h0 = ht * 128;

    const int tid  = threadIdx.x;
    const int wave = tid >> 6;
    const int lane = tid & 63;
    const int wr = wave >> 1, wc = wave & 1;   // 2x2 wave grid
    const int cr = lane & 15;
    const int cg = lane >> 4;

    __shared__ __hip_bfloat16 Al[128 * 64];
    __shared__ __hip_bfloat16 Bl[128 * 64];

    f32x4_t acc[4][4];
    #pragma unroll
    for (int m = 0; m < 4; ++m)
        #pragma unroll
        for (int n = 0; n < 4; ++n)
            acc[m][n] = (f32x4_t){0.f, 0.f, 0.f, 0.f};

    const int colb  = (tid & 7) * 16;   // byte col within 128B LDS row
    const int rbase = tid >> 3;         // 0..31

    for (int kt = 0; kt < 16; ++kt) {
        __syncthreads();
        #pragma unroll
        for (int i = 0; i < 4; ++i) {
            const int row   = i * 32 + rbase;
            const int scolb = colb ^ ((row & 7) << 4);
            const __hip_bfloat16* bg =
                Wb + (((size_t)(h0 + row)) << 10) + kt * 64 + (scolb >> 1);
            gload16(bg, (char*)Bl + (i * 256 + tid) * 16);
            if (AMODE == 0) {
                const __hip_bfloat16* ag =
                    encb + (((size_t)b * S + s0 + row) << 10) + kt * 64 + (scolb >> 1);
                gload16(ag, (char*)Al + (i * 256 + tid) * 16);
            } else {
                const float* af =
                    enc + (((size_t)b * S + s0 + row) << 10) + kt * 64 + (tid & 7) * 8;
                bf16x8_t v8 = cvt8(*(const float4*)af, *(const float4*)(af + 4));
                *(bf16x8_t*)((char*)Al + row * 128 + scolb) = v8;
            }
        }
        __syncthreads();

        bf16x8_t afr[2][4], bfr[2][4];
        #pragma unroll
        for (int ks = 0; ks < 2; ++ks) {
            #pragma unroll
            for (int m = 0; m < 4; ++m) {
                const int arow  = wr * 64 + m * 16 + cr;
                const int acolb = (ks * 64 + cg * 16) ^ ((arow & 7) << 4);
                afr[ks][m] = *(const bf16x8_t*)((const char*)Al + arow * 128 + acolb);
                const int brow  = wc * 64 + m * 16 + cr;
                const int bcolb = (ks * 64 + cg * 16) ^ ((brow & 7) << 4);
                bfr[ks][m] = *(const bf16x8_t*)((const char*)Bl + brow * 128 + bcolb);
            }
        }
        #pragma unroll
        for (int ks = 0; ks < 2; ++ks)
            #pragma unroll
            for (int m = 0; m < 4; ++m)
                #pragma unroll
                for (int n = 0; n < 4; ++n)
                    acc[m][n] = __builtin_amdgcn_mfma_f32_16x16x32_bf16(
                        afr[ks][m], bfr[ks][n], acc[m][n], 0, 0, 0);
    }

    // Epilogue: x = acc + dec_proj; t = v*tanh(x); reduce over 16 h-cols/lane-group.
    float vv[4], dp[4];
    #pragma unroll
    for (int n = 0; n < 4; ++n) {
        int h = h0 + wc * 64 + n * 16 + cr;
        vv[n] = v[h];
        dp[n] = dec_proj[b * H + h];
    }
    #pragma unroll
    for (int m = 0; m < 4; ++m) {
        #pragma unroll
        for (int j = 0; j < 4; ++j) {
            float t = 0.f;
            #pragma unroll
            for (int n = 0; n < 4; ++n)
                t += vv[n] * fast_tanh(acc[m][n][j] + dp[n]);
            t += __shfl_xor(t, 1);
            t += __shfl_xor(t, 2);
            t += __shfl_xor(t, 4);
            t += __shfl_xor(t, 8);
            if (cr == 0) {
                int srow = s0 + wr * 64 + m * 16 + cg * 4 + j;
                part[(size_t)(b * S + srow) * 16 + ht * 2 + wc] = t;
            }
        }
    }
}

// K3: sum 16 partials -> logit; masked softmax over s per batch
__global__ __launch_bounds__(256) void k3_softmax(
    const float* __restrict__ part, const int* __restrict__ seq,
    float* __restrict__ attn)
{
    int b = blockIdx.x, tid = threadIdx.x;
    int len = seq[b];
    float vals[8];
    float mx = -3.4e38f;
    #pragma unroll
    for (int i = 0; i < 8; ++i) {
        int s = i * 256 + tid;
        float x = MASK_VAL;
        if (s < len) {
            const f32x4_t* p = (const f32x4_t*)&part[(size_t)(b * S + s) * 16];
            f32x4_t a = p[0], c = p[1], d = p[2], e = p[3];
            x = (a[0] + a[1] + a[2] + a[3]) + (c[0] + c[1] + c[2] + c[3]) +
                (d[0] + d[1] + d[2] + d[3]) + (e[0] + e[1] + e[2] + e[3]);
        }
        vals[i] = x;
        mx = fmaxf(mx, x);
    }
    #pragma unroll
    for (int off = 1; off < 64; off <<= 1) mx = fmaxf(mx, __shfl_xor(mx, off));
    __shared__ float red[8];
    int wave = tid >> 6, lane = tid & 63;
    if (lane == 0) red[wave] = mx;
    __syncthreads();
    mx = fmaxf(fmaxf(red[0], red[1]), fmaxf(red[2], red[3]));
    float e[8];
    float sum = 0.f;
    #pragma unroll
    for (int i = 0; i < 8; ++i) { e[i] = __expf(vals[i] - mx); sum += e[i]; }
    #pragma unroll
    for (int off = 1; off < 64; off <<= 1) sum += __shfl_xor(sum, off);
    if (lane == 0) red[4 + wave] = sum;
    __syncthreads();
    sum = red[4] + red[5] + red[6] + red[7];
    float inv = 1.0f / sum;
    #pragma unroll
    for (int i = 0; i < 8; ++i) attn[b * S + i * 256 + tid] = e[i] * inv;
}

// K4: opart[b][c][e] = sum_{s in chunk c} attn[b][s] * enc[b][s][e]
__global__ __launch_bounds__(256) void k4_partial(
    const float* __restrict__ enc, const float* __restrict__ attn,
    const int* __restrict__ seq, float* __restrict__ opart)
{
    int c = blockIdx.x, b = blockIdx.y, tid = threadIdx.x;
    int base_s = c * 256;
    int len = seq[b];
    float4 acc = make_float4(0.f, 0.f, 0.f, 0.f);
    if (base_s < len) {
        int s_end = min(256, len - base_s);
        const float* ep = enc + ((size_t)b * S + base_s) * E + tid * 4;
        const float* ap = attn + b * S + base_s;
        for (int s = 0; s < s_end; ++s) {
            float w = ap[s];
            float4 ev = *(const float4*)ep;
            ep += E;
            acc.x += w * ev.x; acc.y += w * ev.y;
            acc.z += w * ev.z; acc.w += w * ev.w;
        }
    }
    *(float4*)(&opart[((b * 8) + c) * 1024 + tid * 4]) = acc;
}

// K5: out[b][e] = sum_c opart[b][c][e]
__global__ __launch_bounds__(256) void k5_reduce(
    const float* __restrict__ opart, float* __restrict__ out)
{
    int gid = blockIdx.x * 256 + threadIdx.x;  // 32768 = B*E
    int b = gid >> 10, e = gid & 1023;
    float s = 0.f;
    #pragma unroll
    for (int c = 0; c < 8; ++c) s += opart[(b * 8 + c) * 1024 + e];
    out[gid] = s;
}

extern "C" void kernel_launch(void* const* d_in, const int* in_sizes, int n_in,
                              void* d_out, int out_size, void* d_ws, size_t ws_size,
                              hipStream_t stream)
{
    const float* enc = (const float*)d_in[0];
    const int*   seq = (const int*)d_in[1];
    const float* dec = (const float*)d_in[2];
    const float* W   = (const float*)d_in[3];
    const float* v   = (const float*)d_in[4];

    float* out  = (float*)d_out;            // (B, E)
    float* attn = out + B * E;              // (B, S)

    float* dec_proj = (float*)d_ws;                         // B*H
    float* part     = dec_proj + B * H;                     // B*S*16
    float* opart    = part + (size_t)B * S * 16;            // B*8*1024
    __hip_bfloat16* Wb = (__hip_bfloat16*)(opart + B * 8 * 1024);  // H*E bf16
    __hip_bfloat16* encb = Wb + (size_t)H * E;                     // B*S*E bf16

    const size_t need = (size_t)(B * H + B * S * 16 + B * 8 * 1024) * 4
                      + (size_t)H * E * 2 + (size_t)B * S * E * 2;
    const bool use_encb = ws_size >= need;

    hipLaunchKernelGGL(kW_conv, dim3(H * E / 1024), dim3(256), 0, stream, W, Wb);
    hipLaunchKernelGGL(k1_decproj, dim3(B * H / 256), dim3(256), 0, stream,
                       dec, W, dec_proj);
    if (use_encb) {
        hipLaunchKernelGGL(k0_encconv, dim3(S / 128, B), dim3(256), 0, stream,
                           enc, seq, encb);
        hipLaunchKernelGGL(k2_mfma<0>, dim3(S / 128, B, H / 128), dim3(256), 0,
                           stream, enc, encb, Wb, v, dec_proj, seq, part);
    } else {
        hipLaunchKernelGGL(k2_mfma<1>, dim3(S / 128, B, H / 128), dim3(256), 0,
                           stream, enc, encb, Wb, v, dec_proj, seq, part);
    }
    hipLaunchKernelGGL(k3_softmax, dim3(B), dim3(256), 0, stream,
                       part, seq, attn);
    hipLaunchKernelGGL(k4_partial, dim3(8, B), dim3(256), 0, stream,
                       enc, attn, seq, opart);
    hipLaunchKernelGGL(k5_reduce, dim3(B * E / 256), dim3(256), 0, stream,
                       opart, out);
}

// Round 4
// 265.156 us; speedup vs baseline: 5.7483x; 1.3883x over previous
//
#include <hip/hip_runtime.h>
#include <hip/hip_bf16.h>

#define B 32
#define S 2048
#define E 1024
#define H 1024
#define MASK_VAL -50000.0f

typedef __attribute__((ext_vector_type(8))) short bf16x8_t;
typedef __attribute__((ext_vector_type(4))) float f32x4_t;

__device__ __forceinline__ float fast_tanh(float x) {
    float a = fabsf(x);
    float e = __expf(-2.0f * a);
    float t = (1.0f - e) / (1.0f + e);
    return copysignf(t, x);
}

__device__ __forceinline__ float b2f(short s) {
    return __uint_as_float(((unsigned)(unsigned short)s) << 16);
}

__device__ __forceinline__ bf16x8_t cvt8(const float4 f0, const float4 f1) {
    union { bf16x8_t s8; __hip_bfloat162 h[4]; } u;
    u.h[0] = __float22bfloat162_rn(make_float2(f0.x, f0.y));
    u.h[1] = __float22bfloat162_rn(make_float2(f0.z, f0.w));
    u.h[2] = __float22bfloat162_rn(make_float2(f1.x, f1.y));
    u.h[3] = __float22bfloat162_rn(make_float2(f1.z, f1.w));
    return u.s8;
}

__device__ __forceinline__ void gload16(const void* g, void* l) {
    __builtin_amdgcn_global_load_lds(
        (const __attribute__((address_space(1))) void*)g,
        (__attribute__((address_space(3))) void*)l, 16, 0, 0);
}

// kprep: blocks 0..1023 = W->bf16 conv; 1024..1151 = dec_proj
__global__ __launch_bounds__(256) void kprep(
    const float* __restrict__ W, const float* __restrict__ dec,
    __hip_bfloat16* __restrict__ Wb, float* __restrict__ dec_proj)
{
    int blk = blockIdx.x, tid = threadIdx.x;
    if (blk < 1024) {
        int idx = (blk * 256 + tid) * 4;   // over H*E
        int h = idx >> 10, e = idx & 1023;
        float4 f = *(const float4*)(W + (size_t)h * 2048 + e);
        __hip_bfloat162 p0 = __float22bfloat162_rn(make_float2(f.x, f.y));
        __hip_bfloat162 p1 = __float22bfloat162_rn(make_float2(f.z, f.w));
        *reinterpret_cast<__hip_bfloat162*>(Wb + idx)     = p0;
        *reinterpret_cast<__hip_bfloat162*>(Wb + idx + 2) = p1;
    } else {
        int gid = (blk - 1024) * 256 + tid;   // 32768 total
        int b = gid >> 10, h = gid & 1023;
        const float4* wd = (const float4*)(W + (size_t)h * 2048 + 1024);
        const float4* dd = (const float4*)(dec + b * 1024);
        float acc = 0.f;
        for (int d = 0; d < 256; ++d) {
            float4 w4 = wd[d], d4 = dd[d];
            acc += w4.x * d4.x + w4.y * d4.y + w4.z * d4.z + w4.w * d4.w;
        }
        dec_proj[gid] = acc;
    }
}

// k0: enc fp32 -> bf16 for active (tile-rounded) rows only
__global__ __launch_bounds__(256) void k0_encconv(
    const float* __restrict__ enc, const int* __restrict__ seq,
    __hip_bfloat16* __restrict__ encb)
{
    int c = blockIdx.x, b = blockIdx.y;
    if (c * 128 >= seq[b]) return;
    size_t base = ((size_t)b * S + c * 128) * E;
    const float* src = enc + base;
    __hip_bfloat16* dst = encb + base;
    int tid = threadIdx.x;
    #pragma unroll 4
    for (int it = 0; it < 64; ++it) {
        int idx = it * 2048 + tid * 8;
        float4 f0 = *(const float4*)(src + idx);
        float4 f1 = *(const float4*)(src + idx + 4);
        *(bf16x8_t*)(dst + idx) = cvt8(f0, f1);
    }
}

// K2: double-buffered bf16 MFMA GEMM, 128(s) x 128(h) tile, BK=64, K=1024.
// T3-minimum 2-phase: stage(next) issued BEFORE compute(cur); the vmcnt(0)
// drain at the single per-iter barrier lands after the MFMAs. LDS XOR-swizzle
// (row&7)<<4 on byte col; gload_lds keeps LDS dest linear, source pre-swizzled.
// Grid flattened; 8 ht-blocks of one (s,b) are 8 apart -> same XCD L2.
template<int AMODE>
__global__ __launch_bounds__(256, 2) void k2_mfma(
    const float* __restrict__ enc, const __hip_bfloat16* __restrict__ encb,
    const __hip_bfloat16* __restrict__ Wb, const float* __restrict__ v,
    const float* __restrict__ dec_proj, const int* __restrict__ seq,
    float* __restrict__ part)
{
    const int bid  = blockIdx.x;
    const int pair = (bid >> 6) * 8 + (bid & 7);   // 0..511 = s-tile + 16*b
    const int ht   = (bid >> 3) & 7;
    const int b    = pair >> 4;
    const int s0   = (pair & 15) * 128;
    if (s0 >= seq[b]) return;
    const int h0 = ht * 128;

    const int tid  = threadIdx.x;
    const int wave = tid >> 6;
    const int lane = tid & 63;
    const int wr = wave >> 1, wc = wave & 1;
    const int cr = lane & 15, cg = lane >> 4;

    __shared__ __hip_bfloat16 Al[2][128 * 64];
    __shared__ __hip_bfloat16 Bl[2][128 * 64];

    const int colb  = (tid & 7) * 16;
    const int rbase = tid >> 3;

    f32x4_t acc[4][4];
    #pragma unroll
    for (int m = 0; m < 4; ++m)
        #pragma unroll
        for (int n = 0; n < 4; ++n)
            acc[m][n] = (f32x4_t){0.f, 0.f, 0.f, 0.f};

    auto stage = [&](int buf, int kt) {
        #pragma unroll
        for (int i = 0; i < 4; ++i) {
            const int row   = i * 32 + rbase;
            const int scolb = colb ^ ((row & 7) << 4);
            const __hip_bfloat16* bg =
                Wb + (((size_t)(h0 + row)) << 10) + kt * 64 + (scolb >> 1);
            gload16(bg, (char*)&Bl[buf][0] + (i * 256 + tid) * 16);
            if (AMODE == 0) {
                const __hip_bfloat16* ag =
                    encb + (((size_t)b * S + s0 + row) << 10) + kt * 64 + (scolb >> 1);
                gload16(ag, (char*)&Al[buf][0] + (i * 256 + tid) * 16);
            } else {
                const float* af =
                    enc + (((size_t)b * S + s0 + row) << 10) + kt * 64 + (tid & 7) * 8;
                bf16x8_t v8 = cvt8(*(const float4*)af, *(const float4*)(af + 4));
                *(bf16x8_t*)((char*)&Al[buf][0] + row * 128 + scolb) = v8;
            }
        }
    };

    stage(0, 0);
    __syncthreads();
    int cur = 0;
    for (int kt = 0; kt < 16; ++kt) {
        if (kt < 15) stage(cur ^ 1, kt + 1);   // loads fly under the MFMAs below
        bf16x8_t afr[2][4], bfr[2][4];
        #pragma unroll
        for (int ks = 0; ks < 2; ++ks) {
            #pragma unroll
            for (int m = 0; m < 4; ++m) {
                const int arow  = wr * 64 + m * 16 + cr;
                const int acolb = (ks * 64 + cg * 16) ^ ((arow & 7) << 4);
                afr[ks][m] = *(const bf16x8_t*)((const char*)&Al[cur][0] + arow * 128 + acolb);
                const int brow  = wc * 64 + m * 16 + cr;
                const int bcolb = (ks * 64 + cg * 16) ^ ((brow & 7) << 4);
                bfr[ks][m] = *(const bf16x8_t*)((const char*)&Bl[cur][0] + brow * 128 + bcolb);
            }
        }
        #pragma unroll
        for (int ks = 0; ks < 2; ++ks)
            #pragma unroll
            for (int m = 0; m < 4; ++m)
                #pragma unroll
                for (int n = 0; n < 4; ++n)
                    acc[m][n] = __builtin_amdgcn_mfma_f32_16x16x32_bf16(
                        afr[ks][m], bfr[ks][n], acc[m][n], 0, 0, 0);
        __syncthreads();   // drains vmcnt(0): buf^1 ready, cur fully consumed
        cur ^= 1;
    }

    // Epilogue: x = acc + dec_proj; t = v*tanh(x); reduce over 16 h-cols/lane-group.
    float vv[4], dp[4];
    #pragma unroll
    for (int n = 0; n < 4; ++n) {
        int h = h0 + wc * 64 + n * 16 + cr;
        vv[n] = v[h];
        dp[n] = dec_proj[b * H + h];
    }
    #pragma unroll
    for (int m = 0; m < 4; ++m) {
        #pragma unroll
        for (int j = 0; j < 4; ++j) {
            float t = 0.f;
            #pragma unroll
            for (int n = 0; n < 4; ++n)
                t += vv[n] * fast_tanh(acc[m][n][j] + dp[n]);
            t += __shfl_xor(t, 1);
            t += __shfl_xor(t, 2);
            t += __shfl_xor(t, 4);
            t += __shfl_xor(t, 8);
            if (cr == 0) {
                int srow = s0 + wr * 64 + m * 16 + cg * 4 + j;
                part[(size_t)(b * S + srow) * 16 + ht * 2 + wc] = t;
            }
        }
    }
}

// K3: sum 16 partials -> logit; masked softmax over s per batch
__global__ __launch_bounds__(256) void k3_softmax(
    const float* __restrict__ part, const int* __restrict__ seq,
    float* __restrict__ attn)
{
    int b = blockIdx.x, tid = threadIdx.x;
    int len = seq[b];
    float vals[8];
    float mx = -3.4e38f;
    #pragma unroll
    for (int i = 0; i < 8; ++i) {
        int s = i * 256 + tid;
        float x = MASK_VAL;
        if (s < len) {
            const f32x4_t* p = (const f32x4_t*)&part[(size_t)(b * S + s) * 16];
            f32x4_t a = p[0], c = p[1], d = p[2], e = p[3];
            x = (a[0] + a[1] + a[2] + a[3]) + (c[0] + c[1] + c[2] + c[3]) +
                (d[0] + d[1] + d[2] + d[3]) + (e[0] + e[1] + e[2] + e[3]);
        }
        vals[i] = x;
        mx = fmaxf(mx, x);
    }
    #pragma unroll
    for (int off = 1; off < 64; off <<= 1) mx = fmaxf(mx, __shfl_xor(mx, off));
    __shared__ float red[8];
    int wave = tid >> 6, lane = tid & 63;
    if (lane == 0) red[wave] = mx;
    __syncthreads();
    mx = fmaxf(fmaxf(red[0], red[1]), fmaxf(red[2], red[3]));
    float e[8];
    float sum = 0.f;
    #pragma unroll
    for (int i = 0; i < 8; ++i) { e[i] = __expf(vals[i] - mx); sum += e[i]; }
    #pragma unroll
    for (int off = 1; off < 64; off <<= 1) sum += __shfl_xor(sum, off);
    if (lane == 0) red[4 + wave] = sum;
    __syncthreads();
    sum = red[4] + red[5] + red[6] + red[7];
    float inv = 1.0f / sum;
    #pragma unroll
    for (int i = 0; i < 8; ++i) attn[b * S + i * 256 + tid] = e[i] * inv;
}

// K4: opart[b][c][so][e] partial weighted sums. AMODE 0: bf16 encb 16B loads;
// AMODE 1: fp32 enc fallback.
template<int AMODE>
__global__ __launch_bounds__(256) void k4_partial(
    const float* __restrict__ enc, const __hip_bfloat16* __restrict__ encb,
    const float* __restrict__ attn, const int* __restrict__ seq,
    float* __restrict__ opart)
{
    int c = blockIdx.x, b = blockIdx.y, tid = threadIdx.x;
    int base_s = c * 256;
    int len = seq[b];
    if (AMODE == 0) {
        int e0 = (tid & 127) * 8;
        int so = tid >> 7;
        float av[8];
        #pragma unroll
        for (int j = 0; j < 8; ++j) av[j] = 0.f;
        if (base_s < len) {
            int s_end = min(256, len - base_s);
            for (int s = so; s < s_end; s += 2) {
                float w = attn[b * S + base_s + s];
                bf16x8_t u = *(const bf16x8_t*)(encb +
                    (((size_t)b * S + base_s + s) << 10) + e0);
                #pragma unroll
                for (int j = 0; j < 8; ++j) av[j] += w * b2f(u[j]);
            }
        }
        float* dst = opart + (((size_t)(b * 8 + c) * 2 + so) << 10) + e0;
        *(float4*)dst       = make_float4(av[0], av[1], av[2], av[3]);
        *(float4*)(dst + 4) = make_float4(av[4], av[5], av[6], av[7]);
    } else {
        float4 acc = make_float4(0.f, 0.f, 0.f, 0.f);
        if (base_s < len) {
            int s_end = min(256, len - base_s);
            const float* ep = enc + ((size_t)b * S + base_s) * E + (tid & 255) * 4;
            const float* ap = attn + b * S + base_s;
            for (int s = 0; s < s_end; ++s) {
                float w = ap[s];
                float4 ev = *(const float4*)ep;
                ep += E;
                acc.x += w * ev.x; acc.y += w * ev.y;
                acc.z += w * ev.z; acc.w += w * ev.w;
            }
        }
        float* dst = opart + (((size_t)(b * 8 + c) * 2) << 10) + tid * 4;
        *(float4*)dst = acc;
        float* dst2 = opart + (((size_t)(b * 8 + c) * 2 + 1) << 10) + tid * 4;
        *(float4*)dst2 = make_float4(0.f, 0.f, 0.f, 0.f);
    }
}

// K5: out[b][e] = sum over 16 partials
__global__ __launch_bounds__(256) void k5_reduce(
    const float* __restrict__ opart, float* __restrict__ out)
{
    int gid = blockIdx.x * 256 + threadIdx.x;  // 32768 = B*E
    int b = gid >> 10, e = gid & 1023;
    float s = 0.f;
    #pragma unroll
    for (int c = 0; c < 16; ++c) s += opart[((size_t)(b * 16 + c) << 10) + e];
    out[gid] = s;
}

extern "C" void kernel_launch(void* const* d_in, const int* in_sizes, int n_in,
                              void* d_out, int out_size, void* d_ws, size_t ws_size,
                              hipStream_t stream)
{
    const float* enc = (const float*)d_in[0];
    const int*   seq = (const int*)d_in[1];
    const float* dec = (const float*)d_in[2];
    const float* W   = (const float*)d_in[3];
    const float* v   = (const float*)d_in[4];

    float* out  = (float*)d_out;            // (B, E)
    float* attn = out + B * E;              // (B, S)

    float* dec_proj = (float*)d_ws;                         // B*H
    float* part     = dec_proj + B * H;                     // B*S*16
    float* opart    = part + (size_t)B * S * 16;            // B*16*1024
    __hip_bfloat16* Wb = (__hip_bfloat16*)(opart + (size_t)B * 16 * 1024);
    __hip_bfloat16* encb = Wb + (size_t)H * E;              // B*S*E bf16

    const size_t need = (size_t)(B * H + B * S * 16 + B * 16 * 1024) * 4
                      + (size_t)H * E * 2 + (size_t)B * S * E * 2;
    const bool use_encb = ws_size >= need;

    hipLaunchKernelGGL(kprep, dim3(1024 + 128), dim3(256), 0, stream,
                       W, dec, Wb, dec_proj);
    if (use_encb) {
        hipLaunchKernelGGL(k0_encconv, dim3(S / 128, B), dim3(256), 0, stream,
                           enc, seq, encb);
        hipLaunchKernelGGL(k2_mfma<0>, dim3(4096), dim3(256), 0, stream,
                           enc, encb, Wb, v, dec_proj, seq, part);
    } else {
        hipLaunchKernelGGL(k2_mfma<1>, dim3(4096), dim3(256), 0, stream,
                           enc, encb, Wb, v, dec_proj, seq, part);
    }
    hipLaunchKernelGGL(k3_softmax, dim3(B), dim3(256), 0, stream,
                       part, seq, attn);
    if (use_encb) {
        hipLaunchKernelGGL(k4_partial<0>, dim3(8, B), dim3(256), 0, stream,
                           enc, encb, attn, seq, opart);
    } else {
        hipLaunchKernelGGL(k4_partial<1>, dim3(8, B), dim3(256), 0, stream,
                           enc, encb, attn, seq, opart);
    }
    hipLaunchKernelGGL(k5_reduce, dim3(B * E / 256), dim3(256), 0, stream,
                       opart, out);
}